// Round 6
// baseline (1021.784 us; speedup 1.0000x reference)
//
#include <hip/hip_runtime.h>
#include <stdint.h>

#define ATOM_FDIM 133
#define BOND_FDIM 147
#define HIDDEN    300
#define N_ATOMS   100000
#define N_BONDS   200000
#define MAX_NB    6
#define N_MOLS    4000

#define KP_I 160      // padded K for W_i GEMM (147)
#define KP_H 320      // padded K for W_h GEMM (300)
#define KP_O 448      // padded K for W_o GEMM (433)
#define LDA  304      // activation row stride in elems (608B, 16B-aligned)
#define CPR  38       // uint4 chunks per activation row (304/8)

#define TM   128      // GEMM tile rows
#define NPAD 384      // GEMM tile cols (padded N, uniform staging)
#define ACH  8        // A chunks (1KB) per K-tile
#define BCH  24       // B chunks (1KB) per K-tile

typedef unsigned short u16;
typedef short bf16x8 __attribute__((ext_vector_type(8)));
typedef float f32x4 __attribute__((ext_vector_type(4)));

__device__ __forceinline__ u16 f2bu(float f) {            // f32 -> bf16 (RNE)
    unsigned u = __float_as_uint(f);
    u += 0x7FFFu + ((u >> 16) & 1u);
    return (u16)(u >> 16);
}
__device__ __forceinline__ float bu2f(u16 b) { return __uint_as_float(((unsigned)b) << 16); }

#define AS1 __attribute__((address_space(1)))
#define AS3 __attribute__((address_space(3)))
__device__ __forceinline__ void gl_lds16(const void* g, void* l) {
    __builtin_amdgcn_global_load_lds((const AS1 void*)g, (AS3 void*)l, 16, 0, 0);
}

// ---------- dense bf16 MFMA GEMM, phase-split double-buffered, 2 blocks/CU ----------
// Block: 128 rows x 384 cols, 512 threads (8 waves, 4x2). Wave: 32 rows x 192
// cols = 2x12 frags of 16x16x32. LDS: 2 bufs x (A 8KB + B 24KB) = 64KB ->
// 2 blocks/CU (16 waves) so vmcnt/barrier stalls of one block are covered by
// the twin block's waves. Per K-step: stage all 4 chunks of tile t+1 early,
// two MFMA clusters with setprio, single vmcnt(0) publish gate at step end
// (~full K-step of latency cover). B staged from contiguous 1KB panels.
// EPI 0: out0=raw, out1=relu | EPI 1: out0=raw | EPI 2: out0=relu(v+bias)
template <int EPI>
__global__ __launch_bounds__(512, 2) void mm_k(
    const u16* __restrict__ A, int lda,
    const u16* __restrict__ Wp,          // panel layout: [NT][BCH][512] elems
    const float* __restrict__ bias,
    u16* __restrict__ out0, int ldo0,
    u16* __restrict__ out1, int ldo1,
    int M, int NT)                       // NT = Kp/32 K-steps
{
    __shared__ __align__(16) u16 As[2][ACH * 512];   // 2 x 8 KB
    __shared__ __align__(16) u16 Bs[2][BCH * 512];   // 2 x 24 KB

    const int t    = threadIdx.x;
    const int lane = t & 63, wid = t >> 6;
    const int fl   = lane & 15, fh = lane >> 4;
    const int m0   = blockIdx.x * TM;
    const int wr   = wid >> 1, wc = wid & 1;

    // A stage source: wave w covers rows [w*16, w*16+16); lane l -> row base+(l&15),
    // 16B at k-seg (l>>4). Pre-swizzled so LDS slot order == fragment order.
    int arow = m0 + wid * 16 + fl;
    if (arow > M - 1) arow = M - 1;
    const size_t srcA = (size_t)arow * (size_t)lda * 2u + (size_t)(fh * 16);
    // B stage source: contiguous 1KB panels; wave w stages chunks 3w..3w+2.
    const size_t srcB = (size_t)(3 * wid) * 1024u + (size_t)lane * 16u;

    char* ldsA_of[2] = { (char*)As[0] + wid * 1024, (char*)As[1] + wid * 1024 };
    char* ldsB_of[2] = { (char*)Bs[0] + 3 * wid * 1024, (char*)Bs[1] + 3 * wid * 1024 };

    f32x4 acc[2][12] = {};

    // prologue: stage tile 0 into buf 0 (4 loads per wave)
    gl_lds16((const char*)A + srcA, ldsA_of[0]);
    #pragma unroll
    for (int j = 0; j < 3; ++j)
        gl_lds16((const char*)Wp + srcB + (size_t)j * 1024, ldsB_of[0] + j * 1024);
    asm volatile("s_waitcnt vmcnt(0)" ::: "memory");
    __builtin_amdgcn_s_barrier();

    int cur = 0;
    for (int tt = 0; tt < NT; ++tt) {
        const int nxt = cur ^ 1;
        int w1 = tt + 1; if (w1 >= NT) w1 = 0;         // wrapped prefetch tile
        const u16* as_c = As[cur];
        const u16* bs_c = Bs[cur];
        const size_t kbA = (size_t)w1 * 64u;
        const size_t kbB = (size_t)w1 * (BCH * 1024u);

        // ---------- phase 1: issue tile t+1 stages, read frags, MFMA cluster 1 ----
        gl_lds16((const char*)A + srcA + kbA, ldsA_of[nxt]);
        #pragma unroll
        for (int j = 0; j < 3; ++j)
            gl_lds16((const char*)Wp + kbB + srcB + (size_t)j * 1024,
                     ldsB_of[nxt] + j * 1024);

        bf16x8 af0, af1, bfv[12];
        af0 = *reinterpret_cast<const bf16x8*>(&as_c[(wr * 2 + 0) * 512 + lane * 8]);
        af1 = *reinterpret_cast<const bf16x8*>(&as_c[(wr * 2 + 1) * 512 + lane * 8]);
        #pragma unroll
        for (int n = 0; n < 6; ++n)
            bfv[n] = *reinterpret_cast<const bf16x8*>(&bs_c[(wc * 12 + n) * 512 + lane * 8]);
        __builtin_amdgcn_s_barrier();
        __builtin_amdgcn_s_setprio(1);
        #pragma unroll
        for (int n = 0; n < 6; ++n) {
            acc[0][n] = __builtin_amdgcn_mfma_f32_16x16x32_bf16(af0, bfv[n], acc[0][n], 0, 0, 0);
            acc[1][n] = __builtin_amdgcn_mfma_f32_16x16x32_bf16(af1, bfv[n], acc[1][n], 0, 0, 0);
        }
        __builtin_amdgcn_s_setprio(0);
        __builtin_amdgcn_s_barrier();

        // ---------- phase 2: read remaining frags, MFMA cluster 2, publish t+1 ----
        #pragma unroll
        for (int n = 6; n < 12; ++n)
            bfv[n] = *reinterpret_cast<const bf16x8*>(&bs_c[(wc * 12 + n) * 512 + lane * 8]);
        __builtin_amdgcn_s_setprio(1);
        #pragma unroll
        for (int n = 6; n < 12; ++n) {
            acc[0][n] = __builtin_amdgcn_mfma_f32_16x16x32_bf16(af0, bfv[n], acc[0][n], 0, 0, 0);
            acc[1][n] = __builtin_amdgcn_mfma_f32_16x16x32_bf16(af1, bfv[n], acc[1][n], 0, 0, 0);
        }
        __builtin_amdgcn_s_setprio(0);
        // tile t+1's 4 loads landed (per-wave), then publish to all waves
        asm volatile("s_waitcnt vmcnt(0)" ::: "memory");
        __builtin_amdgcn_s_barrier();

        cur = nxt;
    }

    // epilogue: C/D col=lane&15, row=(lane>>4)*4+reg
    #pragma unroll
    for (int m = 0; m < 2; ++m) {
        #pragma unroll
        for (int r = 0; r < 4; ++r) {
            const int row = m0 + wr * 32 + m * 16 + fh * 4 + r;
            if (row >= M) continue;
            #pragma unroll
            for (int n = 0; n < 12; ++n) {
                const int col = wc * 192 + n * 16 + fl;
                if (col >= HIDDEN) continue;
                const float v = acc[m][n][r];
                if (EPI == 0) {
                    out0[(size_t)row * ldo0 + col] = f2bu(v);
                    out1[(size_t)row * ldo1 + col] = f2bu(fmaxf(v, 0.f));
                } else if (EPI == 1) {
                    out0[(size_t)row * ldo0 + col] = f2bu(v);
                } else {
                    out0[(size_t)row * ldo0 + col] = f2bu(fmaxf(v + bias[col], 0.f));
                }
            }
        }
    }
}

// ---- weight -> staged panel layout: Wp[kt][c][l][e] with
//      col = c*16 + (l&15), k = kt*32 + (l>>4)*8 + e ----
__global__ __launch_bounds__(256) void wconv_k(const float* __restrict__ W, int Ks, int NT,
                                               u16* __restrict__ Wp)
{
    const int id = blockIdx.x * 256 + threadIdx.x;
    if (id >= NT * BCH * 512) return;
    const int block = id >> 9, rem = id & 511;
    const int l = rem >> 3, e = rem & 7;
    const int c = block % BCH, kt = block / BCH;
    const int col = c * 16 + (l & 15);
    const int k   = kt * 32 + (l >> 4) * 8 + e;
    const float v = (col < HIDDEN && k < Ks) ? W[(size_t)k * HIDDEN + col] : 0.f;
    Wp[id] = f2bu(v);
}

// ---- f_bonds f32 -> bf16 padded [200000][160] ----
__global__ __launch_bounds__(256) void fbconv_k(const float* __restrict__ fb, u16* __restrict__ dst)
{
    const int id = blockIdx.x * 256 + threadIdx.x;
    if (id >= N_BONDS * KP_I) return;
    const int r = id / KP_I, k = id - r * KP_I;
    dst[id] = f2bu(k < BOND_FDIM ? fb[(size_t)r * BOND_FDIM + k] : 0.f);
}

// ---- dst[a][:] = sum_j src[a2b[a][j]][:]   (16B chunks, stride LDA) ----
__global__ __launch_bounds__(256) void agg_k(const u16* __restrict__ src,
                                             const int* __restrict__ a2b,
                                             u16* __restrict__ dst)
{
    const int c = blockIdx.x * 256 + threadIdx.x;
    if (c >= N_ATOMS * CPR) return;
    const int a = c / CPR, q = c - a * CPR;
    const int h = q * 8;
    const int* nb = a2b + (size_t)a * MAX_NB;
    float s[8] = {};
    #pragma unroll
    for (int j = 0; j < MAX_NB; ++j) {
        const int r = nb[j];
        union { uint4 u; u16 s[8]; } x;
        x.u = *(const uint4*)(src + (size_t)r * LDA + h);
        #pragma unroll
        for (int e = 0; e < 8; ++e) s[e] += bu2f(x.s[e]);
    }
    union { uint4 u; u16 s[8]; } o;
    #pragma unroll
    for (int e = 0; e < 8; ++e) o.s[e] = f2bu(s[e]);
    *(uint4*)(dst + (size_t)a * LDA + h) = o.u;
}

// ---- msg[b] = relu(inp[b] + aY[b2a[b]] - Y[b2revb[b]])   (16B chunks) ----
__global__ __launch_bounds__(256) void comb_k(const u16* __restrict__ inp,
                                              const u16* __restrict__ aY,
                                              const u16* __restrict__ Y,
                                              const int* __restrict__ b2a,
                                              const int* __restrict__ b2revb,
                                              u16* __restrict__ msg)
{
    const int c = blockIdx.x * 256 + threadIdx.x;
    if (c >= N_BONDS * CPR) return;
    const int b = c / CPR, q = c - b * CPR;
    const int h = q * 8;
    const int ia = b2a[b], ir = b2revb[b];
    union { uint4 u; u16 s[8]; } xi, xa, xy, o;
    xi.u = *(const uint4*)(inp + (size_t)b * LDA + h);
    xa.u = *(const uint4*)(aY + (size_t)ia * LDA + h);
    xy.u = *(const uint4*)(Y + (size_t)ir * LDA + h);
    #pragma unroll
    for (int j = 0; j < 8; ++j)
        o.s[j] = f2bu(fmaxf(bu2f(xi.s[j]) + bu2f(xa.s[j]) - bu2f(xy.s[j]), 0.f));
    *(uint4*)(msg + (size_t)b * LDA + h) = o.u;
}

// ---- concat[a][k] : k<133 f_atoms | k<433 amsg | 0 ----
__global__ __launch_bounds__(256) void concat_k(const float* __restrict__ fa,
                                                const u16* __restrict__ amsg,
                                                u16* __restrict__ dst)
{
    const int id = blockIdx.x * 256 + threadIdx.x;
    if (id >= N_ATOMS * KP_O) return;
    const int a = id / KP_O, k = id - a * KP_O;
    float v;
    if (k < ATOM_FDIM)                 v = fa[(size_t)a * ATOM_FDIM + k];
    else if (k < ATOM_FDIM + HIDDEN)   v = bu2f(amsg[(size_t)a * LDA + (k - ATOM_FDIM)]);
    else                               v = 0.f;
    dst[id] = f2bu(v);
}

// ---- per-mol mean over sorted atom2mol ----
__global__ __launch_bounds__(320) void pool_k(const u16* __restrict__ ah,
                                              const int* __restrict__ a2m,
                                              float* __restrict__ out)
{
    const int m = blockIdx.x;
    int lo, hi;
    { int l = 0, r = N_ATOMS;
      while (l < r) { int mid = (l + r) >> 1; if (a2m[mid] < m) l = mid + 1; else r = mid; }
      lo = l; }
    { int l = lo, r = N_ATOMS;
      while (l < r) { int mid = (l + r) >> 1; if (a2m[mid] < m + 1) l = mid + 1; else r = mid; }
      hi = l; }
    const float inv = 1.0f / (float)((hi - lo) > 1 ? (hi - lo) : 1);
    const int h = threadIdx.x;
    if (h >= HIDDEN) return;
    float s = 0.f;
    for (int a = lo; a < hi; ++a) s += bu2f(ah[(size_t)a * LDA + h]);
    out[(size_t)m * HIDDEN + h] = s * inv;
}

extern "C" void kernel_launch(void* const* d_in, const int* in_sizes, int n_in,
                              void* d_out, int out_size, void* d_ws, size_t ws_size,
                              hipStream_t stream)
{
    const float* f_atoms  = (const float*)d_in[0];
    const float* f_bonds  = (const float*)d_in[1];
    const int*   a2b      = (const int*)d_in[2];
    const int*   b2a      = (const int*)d_in[3];
    const int*   b2revb   = (const int*)d_in[4];
    const int*   atom2mol = (const int*)d_in[5];
    const float* W_i      = (const float*)d_in[6];
    const float* W_h      = (const float*)d_in[7];
    const float* W_o_w    = (const float*)d_in[8];
    const float* W_o_b    = (const float*)d_in[9];
    float* out = (float*)d_out;

    // ---- workspace layout (all bf16 as u16); +16 rows slack per big buffer ----
    char* p = (char*)d_ws;
    auto alloc = [&](size_t bytes) { char* r = p; p += (bytes + 255) & ~(size_t)255; return r; };
    u16* inp = (u16*)alloc(((size_t)N_BONDS + 16) * LDA * 2);   // 121.6 MB
    u16* msg = (u16*)alloc(((size_t)N_BONDS + 16) * LDA * 2);   // 121.6 MB
    u16* Yb  = (u16*)alloc(((size_t)N_BONDS + 16) * LDA * 2);   // 121.6 MB; hosts fb16/concat too
    u16* aY  = (u16*)alloc(((size_t)N_ATOMS + 16) * LDA * 2);   //  60.8 MB
    u16* Wpi = (u16*)alloc((size_t)(KP_I / 32) * BCH * 512 * 2);
    u16* Wph = (u16*)alloc((size_t)(KP_H / 32) * BCH * 512 * 2);
    u16* Wpo = (u16*)alloc((size_t)(KP_O / 32) * BCH * 512 * 2);
    if ((size_t)(p - (char*)d_ws) > ws_size) return;

    u16* fb16   = Yb;   // [200000][160], dead before first Y write
    u16* concat = Yb;   // [100000][448], built after Y dead
    u16* ah     = msg;  // [100000][LDA], msg dead after final agg

    const dim3 blk(256);
    auto g1 = [](long long n) { return dim3((unsigned)((n + 255) / 256)); };
    const dim3 blk5(512);
    const dim3 gB((N_BONDS + TM - 1) / TM);   // 1563
    const dim3 gA((N_ATOMS + TM - 1) / TM);   //  782

    wconv_k<<<g1((long long)(KP_I / 32) * BCH * 512), blk, 0, stream>>>(W_i, BOND_FDIM, KP_I / 32, Wpi);
    wconv_k<<<g1((long long)(KP_H / 32) * BCH * 512), blk, 0, stream>>>(W_h, HIDDEN, KP_H / 32, Wph);
    wconv_k<<<g1((long long)(KP_O / 32) * BCH * 512), blk, 0, stream>>>(W_o_w, ATOM_FDIM + HIDDEN, KP_O / 32, Wpo);
    fbconv_k<<<g1((long long)N_BONDS * KP_I), blk, 0, stream>>>(f_bonds, fb16);

    // inp = f_bonds @ W_i ; msg = relu(inp)
    mm_k<0><<<gB, blk5, 0, stream>>>(fb16, KP_I, Wpi, nullptr,
                                     inp, LDA, msg, LDA, N_BONDS, KP_I / 32);

    for (int it = 0; it < 2; ++it) {   // DEPTH-1
        mm_k<1><<<gB, blk5, 0, stream>>>(msg, LDA, Wph, nullptr,
                                         Yb, LDA, nullptr, 0, N_BONDS, KP_H / 32);
        agg_k<<<g1((long long)N_ATOMS * CPR), blk, 0, stream>>>(Yb, a2b, aY);
        comb_k<<<g1((long long)N_BONDS * CPR), blk, 0, stream>>>(inp, aY, Yb, b2a, b2revb, msg);
    }

    agg_k<<<g1((long long)N_ATOMS * CPR), blk, 0, stream>>>(msg, a2b, aY);
    concat_k<<<g1((long long)N_ATOMS * KP_O), blk, 0, stream>>>(f_atoms, aY, concat);
    mm_k<2><<<gA, blk5, 0, stream>>>(concat, KP_O, Wpo, W_o_b,
                                     ah, LDA, nullptr, 0, N_ATOMS, KP_O / 32);
    pool_k<<<dim3(N_MOLS), dim3(320), 0, stream>>>(ah, atom2mol, out);
}

// Round 7
// 950.666 us; speedup vs baseline: 1.0748x; 1.0748x over previous
//
#include <hip/hip_runtime.h>
#include <stdint.h>

#define ATOM_FDIM 133
#define BOND_FDIM 147
#define HIDDEN    300
#define N_ATOMS   100000
#define N_BONDS   200000
#define MAX_NB    6
#define N_MOLS    4000

#define KP_I 160      // padded K for W_i GEMM (147)
#define KP_H 320      // padded K for W_h GEMM (300)
#define KP_O 448      // padded K for output GEMM (433, reordered: amsg|f_atoms|0)
#define LDA  304      // activation row stride in elems (608B, 16B-aligned)
#define CPR  38       // uint4 chunks per activation row (304/8)

#define TM   128      // GEMM tile rows
#define ACH  8        // A chunks (1KB) per K-tile
#define BCH  24       // B chunks (1KB) per K-tile

typedef unsigned short u16;
typedef short bf16x8 __attribute__((ext_vector_type(8)));
typedef float f32x4 __attribute__((ext_vector_type(4)));

__device__ __forceinline__ u16 f2bu(float f) {            // f32 -> bf16 (RNE)
    unsigned u = __float_as_uint(f);
    u += 0x7FFFu + ((u >> 16) & 1u);
    return (u16)(u >> 16);
}
__device__ __forceinline__ float bu2f(u16 b) { return __uint_as_float(((unsigned)b) << 16); }

#define AS1 __attribute__((address_space(1)))
#define AS3 __attribute__((address_space(3)))
__device__ __forceinline__ void gl_lds16(const void* g, void* l) {
    __builtin_amdgcn_global_load_lds((const AS1 void*)g, (AS3 void*)l, 16, 0, 0);
}

// ---------- dense bf16 MFMA GEMM: quad-buffered, 1 barrier / K-step ----------
// Block: 128 rows x 384 cols, 512 threads (8 waves, 4x2). Wave: 32 rows x 192
// cols = 2x12 frags of 16x16x32. LDS: 4 bufs x (A 8KB + B 24KB) = 128KB.
// Per K-step: STAGE tile t+3 (4 gl_lds/wave) -> 14 ds_reads -> setprio + 24
// MFMA -> vmcnt(8) (waits T(t+1), issued 3 steps ago; never drains) ->
// s_barrier. WAR on the stage target is protected by the previous step's
// barrier (that buffer was last read 3 steps ago). Fragment-ordered LDS via
// pre-swizzled global sources: all frag reads are contiguous lane*16B.
// EPI 0: out0=raw, out1=relu | EPI 1: out0=raw | EPI 2: out0=relu(v+bias)
template <int EPI>
__global__ __launch_bounds__(512, 2) void mm_k(
    const u16* __restrict__ A, int lda,
    const u16* __restrict__ Wp,          // panel layout: [NT][BCH][512] elems
    const float* __restrict__ bias,
    u16* __restrict__ out0, int ldo0,
    u16* __restrict__ out1, int ldo1,
    int M, int NT)                       // NT = Kp/32 K-steps (>= 4)
{
    __shared__ __align__(16) u16 As[4 * ACH * 512];   // 4 x 8 KB
    __shared__ __align__(16) u16 Bs[4 * BCH * 512];   // 4 x 24 KB

    const int t    = threadIdx.x;
    const int lane = t & 63, wid = t >> 6;
    const int fl   = lane & 15, fh = lane >> 4;
    const int m0   = blockIdx.x * TM;
    const int wr   = wid >> 1, wc = wid & 1;

    // A stage source: wave w covers rows [w*16, w*16+16); lane l -> row base+(l&15),
    // 16B at k-seg (l>>4). Pre-swizzled so LDS slot order == fragment order.
    int arow = m0 + wid * 16 + fl;
    if (arow > M - 1) arow = M - 1;
    const size_t srcA = (size_t)arow * (size_t)lda * 2u + (size_t)(fh * 16);
    // B stage source: contiguous 1KB panels; wave w stages chunks 3w..3w+2.
    const size_t srcB = (size_t)(3 * wid) * 1024u + (size_t)lane * 16u;

    char* ldsAbase = (char*)As + wid * 1024;
    char* ldsBbase = (char*)Bs + 3 * wid * 1024;

#define STAGE(buf, kt) do {                                               \
        const size_t kbA_ = (size_t)(kt) * 64u;                           \
        const size_t kbB_ = (size_t)(kt) * (size_t)(BCH * 1024);          \
        char* la_ = ldsAbase + (size_t)(buf) * (ACH * 1024);              \
        char* lb_ = ldsBbase + (size_t)(buf) * (BCH * 1024);              \
        gl_lds16((const char*)A + srcA + kbA_, la_);                      \
        gl_lds16((const char*)Wp + kbB_ + srcB,        lb_);              \
        gl_lds16((const char*)Wp + kbB_ + srcB + 1024, lb_ + 1024);       \
        gl_lds16((const char*)Wp + kbB_ + srcB + 2048, lb_ + 2048);       \
    } while (0)

    f32x4 acc[2][12] = {};

    // prologue: stage tiles 0,1,2 (12 loads/wave); wait to 8 outstanding -> T0 landed
    STAGE(0, 0);
    STAGE(1, 1);
    STAGE(2, 2);
    asm volatile("s_waitcnt vmcnt(8)" ::: "memory");
    __builtin_amdgcn_s_barrier();

    int cur = 0;
    for (int tt = 0; tt < NT; ++tt) {
        int w3 = tt + 3; if (w3 >= NT) w3 -= NT;   // wrapped prefetch tile
        const int nx3 = (cur + 3) & 3;
        STAGE(nx3, w3);

        const u16* as_c = As + cur * (ACH * 512);
        const u16* bs_c = Bs + cur * (BCH * 512);
        bf16x8 af0, af1, bfv[12];
        af0 = *reinterpret_cast<const bf16x8*>(&as_c[(wr * 2 + 0) * 512 + lane * 8]);
        af1 = *reinterpret_cast<const bf16x8*>(&as_c[(wr * 2 + 1) * 512 + lane * 8]);
        #pragma unroll
        for (int n = 0; n < 12; ++n)
            bfv[n] = *reinterpret_cast<const bf16x8*>(&bs_c[(wc * 12 + n) * 512 + lane * 8]);

        __builtin_amdgcn_s_setprio(1);
        #pragma unroll
        for (int n = 0; n < 12; ++n) {
            acc[0][n] = __builtin_amdgcn_mfma_f32_16x16x32_bf16(af0, bfv[n], acc[0][n], 0, 0, 0);
            acc[1][n] = __builtin_amdgcn_mfma_f32_16x16x32_bf16(af1, bfv[n], acc[1][n], 0, 0, 0);
        }
        __builtin_amdgcn_s_setprio(0);

        // counted gate: newest 8 (tiles t+2, t+3) stay in flight; t+1 landed
        asm volatile("s_waitcnt vmcnt(8)" ::: "memory");
        __builtin_amdgcn_s_barrier();

        cur = (cur + 1) & 3;
    }
#undef STAGE

    // epilogue: C/D col=lane&15, row=(lane>>4)*4+reg
    #pragma unroll
    for (int m = 0; m < 2; ++m) {
        #pragma unroll
        for (int r = 0; r < 4; ++r) {
            const int row = m0 + wr * 32 + m * 16 + fh * 4 + r;
            if (row >= M) continue;
            #pragma unroll
            for (int n = 0; n < 12; ++n) {
                const int col = wc * 192 + n * 16 + fl;
                if (col >= HIDDEN) continue;
                const float v = acc[m][n][r];
                if (EPI == 0) {
                    out0[(size_t)row * ldo0 + col] = f2bu(v);
                    out1[(size_t)row * ldo1 + col] = f2bu(fmaxf(v, 0.f));
                } else if (EPI == 1) {
                    out0[(size_t)row * ldo0 + col] = f2bu(v);
                } else {
                    out0[(size_t)row * ldo0 + col] = f2bu(fmaxf(v + bias[col], 0.f));
                }
            }
        }
    }
}

// ---- weight -> staged panel layout with optional K-row remap:
//      col = c*16 + (l&15), k = kt*32 + (l>>4)*8 + e
//      src row r = (k<split) ? k+off1 : k-split; valid iff (k<split ? r<Ktot : r<off1)
__global__ __launch_bounds__(256) void wconv_k(const float* __restrict__ W,
                                               int split, int off1, int Ktot, int NT,
                                               u16* __restrict__ Wp)
{
    const int id = blockIdx.x * 256 + threadIdx.x;
    if (id >= NT * BCH * 512) return;
    const int block = id >> 9, rem = id & 511;
    const int l = rem >> 3, e = rem & 7;
    const int c = block % BCH, kt = block / BCH;
    const int col = c * 16 + (l & 15);
    const int k   = kt * 32 + (l >> 4) * 8 + e;
    float v = 0.f;
    if (col < HIDDEN) {
        if (k < split) {
            const int r = k + off1;
            if (r < Ktot) v = W[(size_t)r * HIDDEN + col];
        } else {
            const int r = k - split;
            if (r < off1) v = W[(size_t)r * HIDDEN + col];
        }
    }
    Wp[id] = f2bu(v);
}

// ---- f_bonds f32 -> bf16 padded [200000][160] ----
__global__ __launch_bounds__(256) void fbconv_k(const float* __restrict__ fb, u16* __restrict__ dst)
{
    const int id = blockIdx.x * 256 + threadIdx.x;
    if (id >= N_BONDS * KP_I) return;
    const int r = id / KP_I, k = id - r * KP_I;
    dst[id] = f2bu(k < BOND_FDIM ? fb[(size_t)r * BOND_FDIM + k] : 0.f);
}

// ---- dst[a][:] = sum_j src[a2b[a][j]][:]   (16B chunks, stride LDA) ----
__global__ __launch_bounds__(256) void agg_k(const u16* __restrict__ src,
                                             const int* __restrict__ a2b,
                                             u16* __restrict__ dst)
{
    const int c = blockIdx.x * 256 + threadIdx.x;
    if (c >= N_ATOMS * CPR) return;
    const int a = c / CPR, q = c - a * CPR;
    const int h = q * 8;
    const int* nb = a2b + (size_t)a * MAX_NB;
    float s[8] = {};
    #pragma unroll
    for (int j = 0; j < MAX_NB; ++j) {
        const int r = nb[j];
        union { uint4 u; u16 s[8]; } x;
        x.u = *(const uint4*)(src + (size_t)r * LDA + h);
        #pragma unroll
        for (int e = 0; e < 8; ++e) s[e] += bu2f(x.s[e]);
    }
    union { uint4 u; u16 s[8]; } o;
    #pragma unroll
    for (int e = 0; e < 8; ++e) o.s[e] = f2bu(s[e]);
    *(uint4*)(dst + (size_t)a * LDA + h) = o.u;
}

// ---- msg[b] = relu(inp[b] + aY[b2a[b]] - Y[b2revb[b]])   (16B chunks) ----
__global__ __launch_bounds__(256) void comb_k(const u16* __restrict__ inp,
                                              const u16* __restrict__ aY,
                                              const u16* __restrict__ Y,
                                              const int* __restrict__ b2a,
                                              const int* __restrict__ b2revb,
                                              u16* __restrict__ msg)
{
    const int c = blockIdx.x * 256 + threadIdx.x;
    if (c >= N_BONDS * CPR) return;
    const int b = c / CPR, q = c - b * CPR;
    const int h = q * 8;
    const int ia = b2a[b], ir = b2revb[b];
    union { uint4 u; u16 s[8]; } xi, xa, xy, o;
    xi.u = *(const uint4*)(inp + (size_t)b * LDA + h);
    xa.u = *(const uint4*)(aY + (size_t)ia * LDA + h);
    xy.u = *(const uint4*)(Y + (size_t)ir * LDA + h);
    #pragma unroll
    for (int j = 0; j < 8; ++j)
        o.s[j] = f2bu(fmaxf(bu2f(xi.s[j]) + bu2f(xa.s[j]) - bu2f(xy.s[j]), 0.f));
    *(uint4*)(msg + (size_t)b * LDA + h) = o.u;
}

// ---- fused final agg + concat (REORDERED): dst[a][k] =
//      k<300: sum_j msg[a2b[a][j]][k] | k<433: f_atoms[a][k-300] | 0
//      (Wpo built with matching row remap). 4 elems (8B) per thread. ----
__global__ __launch_bounds__(256) void aggcat_k(const u16* __restrict__ msg,
                                                const int* __restrict__ a2b,
                                                const float* __restrict__ fa,
                                                u16* __restrict__ dst)
{
    const int id = blockIdx.x * 256 + threadIdx.x;
    if (id >= N_ATOMS * (KP_O / 4)) return;
    const int a = id / (KP_O / 4), c = id - a * (KP_O / 4);
    const int e0 = c * 4;
    union { uint2 u; u16 s[4]; } o;
    if (e0 < HIDDEN) {   // agg region (300 % 4 == 0: no straddle)
        const int* nb = a2b + (size_t)a * MAX_NB;
        float s0 = 0.f, s1 = 0.f, s2 = 0.f, s3 = 0.f;
        #pragma unroll
        for (int j = 0; j < MAX_NB; ++j) {
            union { uint2 u; u16 s[4]; } x;
            x.u = *(const uint2*)(msg + (size_t)nb[j] * LDA + e0);
            s0 += bu2f(x.s[0]); s1 += bu2f(x.s[1]); s2 += bu2f(x.s[2]); s3 += bu2f(x.s[3]);
        }
        o.s[0] = f2bu(s0); o.s[1] = f2bu(s1); o.s[2] = f2bu(s2); o.s[3] = f2bu(s3);
    } else {             // f_atoms region
        #pragma unroll
        for (int j = 0; j < 4; ++j) {
            const int fi = e0 + j - HIDDEN;
            o.s[j] = (fi < ATOM_FDIM) ? f2bu(fa[(size_t)a * ATOM_FDIM + fi]) : (u16)0;
        }
    }
    *(uint2*)(dst + (size_t)a * KP_O + e0) = o.u;
}

// ---- per-mol mean over sorted atom2mol ----
__global__ __launch_bounds__(320) void pool_k(const u16* __restrict__ ah,
                                              const int* __restrict__ a2m,
                                              float* __restrict__ out)
{
    const int m = blockIdx.x;
    int lo, hi;
    { int l = 0, r = N_ATOMS;
      while (l < r) { int mid = (l + r) >> 1; if (a2m[mid] < m) l = mid + 1; else r = mid; }
      lo = l; }
    { int l = lo, r = N_ATOMS;
      while (l < r) { int mid = (l + r) >> 1; if (a2m[mid] < m + 1) l = mid + 1; else r = mid; }
      hi = l; }
    const float inv = 1.0f / (float)((hi - lo) > 1 ? (hi - lo) : 1);
    const int h = threadIdx.x;
    if (h >= HIDDEN) return;
    float s = 0.f;
    for (int a = lo; a < hi; ++a) s += bu2f(ah[(size_t)a * LDA + h]);
    out[(size_t)m * HIDDEN + h] = s * inv;
}

extern "C" void kernel_launch(void* const* d_in, const int* in_sizes, int n_in,
                              void* d_out, int out_size, void* d_ws, size_t ws_size,
                              hipStream_t stream)
{
    const float* f_atoms  = (const float*)d_in[0];
    const float* f_bonds  = (const float*)d_in[1];
    const int*   a2b      = (const int*)d_in[2];
    const int*   b2a      = (const int*)d_in[3];
    const int*   b2revb   = (const int*)d_in[4];
    const int*   atom2mol = (const int*)d_in[5];
    const float* W_i      = (const float*)d_in[6];
    const float* W_h      = (const float*)d_in[7];
    const float* W_o_w    = (const float*)d_in[8];
    const float* W_o_b    = (const float*)d_in[9];
    float* out = (float*)d_out;

    // ---- workspace layout (all bf16 as u16); +16 rows slack per big buffer ----
    char* p = (char*)d_ws;
    auto alloc = [&](size_t bytes) { char* r = p; p += (bytes + 255) & ~(size_t)255; return r; };
    u16* inp = (u16*)alloc(((size_t)N_BONDS + 16) * LDA * 2);   // 121.6 MB
    u16* msg = (u16*)alloc(((size_t)N_BONDS + 16) * LDA * 2);   // 121.6 MB
    u16* Yb  = (u16*)alloc(((size_t)N_BONDS + 16) * LDA * 2);   // 121.6 MB; hosts fb16/concat too
    u16* aY  = (u16*)alloc(((size_t)N_ATOMS + 16) * LDA * 2);   //  60.8 MB
    u16* Wpi = (u16*)alloc((size_t)(KP_I / 32) * BCH * 512 * 2);
    u16* Wph = (u16*)alloc((size_t)(KP_H / 32) * BCH * 512 * 2);
    u16* Wpo = (u16*)alloc((size_t)(KP_O / 32) * BCH * 512 * 2);
    if ((size_t)(p - (char*)d_ws) > ws_size) return;

    u16* fb16   = Yb;   // [200000][160], dead before first Y write
    u16* concat = Yb;   // [100000][448], built after Y dead
    u16* ah     = msg;  // [100000][LDA], msg dead after aggcat

    const dim3 blk(256);
    auto g1 = [](long long n) { return dim3((unsigned)((n + 255) / 256)); };
    const dim3 blk5(512);
    const dim3 gB((N_BONDS + TM - 1) / TM);   // 1563
    const dim3 gA((N_ATOMS + TM - 1) / TM);   //  782

    const int BIGSPLIT = 1 << 20;
    wconv_k<<<g1((long long)(KP_I / 32) * BCH * 512), blk, 0, stream>>>(
        W_i, BIGSPLIT, 0, BOND_FDIM, KP_I / 32, Wpi);
    wconv_k<<<g1((long long)(KP_H / 32) * BCH * 512), blk, 0, stream>>>(
        W_h, BIGSPLIT, 0, HIDDEN, KP_H / 32, Wph);
    // output GEMM: k<300 -> W_o_w row 133+k (amsg part); k>=300 -> row k-300 (f_atoms part)
    wconv_k<<<g1((long long)(KP_O / 32) * BCH * 512), blk, 0, stream>>>(
        W_o_w, HIDDEN, ATOM_FDIM, ATOM_FDIM + HIDDEN, KP_O / 32, Wpo);
    fbconv_k<<<g1((long long)N_BONDS * KP_I), blk, 0, stream>>>(f_bonds, fb16);

    // inp = f_bonds @ W_i ; msg = relu(inp)
    mm_k<0><<<gB, blk5, 0, stream>>>(fb16, KP_I, Wpi, nullptr,
                                     inp, LDA, msg, LDA, N_BONDS, KP_I / 32);

    for (int it = 0; it < 2; ++it) {   // DEPTH-1
        mm_k<1><<<gB, blk5, 0, stream>>>(msg, LDA, Wph, nullptr,
                                         Yb, LDA, nullptr, 0, N_BONDS, KP_H / 32);
        agg_k<<<g1((long long)N_ATOMS * CPR), blk, 0, stream>>>(Yb, a2b, aY);
        comb_k<<<g1((long long)N_BONDS * CPR), blk, 0, stream>>>(inp, aY, Yb, b2a, b2revb, msg);
    }

    // fused final aggregation + concat (reordered), then output GEMM
    aggcat_k<<<g1((long long)N_ATOMS * (KP_O / 4)), blk, 0, stream>>>(msg, a2b, f_atoms, concat);
    mm_k<2><<<gA, blk5, 0, stream>>>(concat, KP_O, Wpo, W_o_b,
                                     ah, LDA, nullptr, 0, N_ATOMS, KP_O / 32);
    pool_k<<<dim3(N_MOLS), dim3(320), 0, stream>>>(ah, atom2mol, out);
}

// Round 8
// 884.431 us; speedup vs baseline: 1.1553x; 1.0749x over previous
//
#include <hip/hip_runtime.h>
#include <stdint.h>

#define ATOM_FDIM 133
#define BOND_FDIM 147
#define HIDDEN    300
#define N_ATOMS   100000
#define N_BONDS   200000
#define MAX_NB    6
#define N_MOLS    4000

#define KP_I 160      // padded K for W_i GEMM (147)
#define KP_H 320      // padded K for W_h GEMM (300)
#define KP_O 448      // padded K for output GEMM (433, reordered: amsg|f_atoms|0)
#define LDA  304      // activation row stride in elems (608B, 16B-aligned)
#define CPR  38       // uint4 chunks per activation row (304/8)

#define TM   128      // GEMM tile rows
#define ACH  8        // A chunks (1KB) per K-tile
#define BCH  24       // B chunks (1KB) per K-tile

typedef unsigned short u16;
typedef short bf16x8 __attribute__((ext_vector_type(8)));
typedef float f32x4 __attribute__((ext_vector_type(4)));

__device__ __forceinline__ u16 f2bu(float f) {            // f32 -> bf16 (RNE)
    unsigned u = __float_as_uint(f);
    u += 0x7FFFu + ((u >> 16) & 1u);
    return (u16)(u >> 16);
}
__device__ __forceinline__ float bu2f(u16 b) { return __uint_as_float(((unsigned)b) << 16); }

__device__ __forceinline__ uint4 relu_bf16x8(uint4 v) {
    union { uint4 u; u16 s[8]; } x, o;
    x.u = v;
    #pragma unroll
    for (int e = 0; e < 8; ++e) o.s[e] = (x.s[e] & 0x8000u) ? (u16)0 : x.s[e];
    return o.u;
}
__device__ __forceinline__ uint4 comb_bf16x8(uint4 vi, uint4 va, uint4 vy) {
    union { uint4 u; u16 s[8]; } xi, xa, xy, o;
    xi.u = vi; xa.u = va; xy.u = vy;
    #pragma unroll
    for (int e = 0; e < 8; ++e)
        o.s[e] = f2bu(fmaxf(bu2f(xi.s[e]) + bu2f(xa.s[e]) - bu2f(xy.s[e]), 0.f));
    return o.u;
}

#define AS1 __attribute__((address_space(1)))
#define AS3 __attribute__((address_space(3)))
__device__ __forceinline__ void gl_lds(const void* g, void* l) {
    __builtin_amdgcn_global_load_lds((const AS1 void*)g, (AS3 void*)l, 16, 0, 0);
}

// ---------- dense bf16 MFMA GEMM on the r5 tri-buffer 2-phase skeleton ----------
// Block: 128 rows x 384 cols, 512 threads (8 waves, 4x2). Wave: 32 rows x 192
// cols = 2x12 frags of 16x16x32. LDS: 3 bufs x (A 8KB + B 24KB) = 96KB.
// A-operand modes (AM):
//   0: dense, staged via global_load_lds 2 tiles ahead (r5-proven).
//   1: A = relu(inp[row]) — per-lane uint4 load 2 tiles ahead, cvt+ds_write 1 ahead.
//   2: A = relu(inp[row] + aY[b2a[row]] - Y[b2revb[row]]) — 3 gathered loads.
// vm ops/step: AM0/1 = 4 -> gate vmcnt(4); AM2 = 6 -> gate vmcnt(6). Never drains.
// Reg double-buffer via 2-unrolled loop with named reg sets (no runtime idx).
// EPI 0: out0 = raw | 1: out0 = relu(v + bias)
template <int AM, int EPI>
__global__ __launch_bounds__(512, 2) void mm_k(
    const u16* __restrict__ A, int lda,          // AM0: dense A; AM1/2: inp
    const u16* __restrict__ aYp,                 // AM2
    const u16* __restrict__ Yp,                  // AM2
    const int* __restrict__ b2a,                 // AM2
    const int* __restrict__ b2revb,              // AM2
    const u16* __restrict__ Wp,                  // panel layout: [NT][BCH][512] elems
    const float* __restrict__ bias,
    u16* __restrict__ out0, int ldo0,
    int M, int NT)                               // AM1/2 require NT even
{
    __shared__ __align__(16) u16 As[3][ACH * 512];   // 3 x 8 KB
    __shared__ __align__(16) u16 Bs[3][BCH * 512];   // 3 x 24 KB

    const int t    = threadIdx.x;
    const int lane = t & 63, wid = t >> 6;
    const int fl   = lane & 15, fh = lane >> 4;
    const int m0   = blockIdx.x * TM;
    const int wr   = wid >> 1, wc = wid & 1;

    int arow = m0 + wid * 16 + fl;
    if (arow > M - 1) arow = M - 1;
    const char* srcAp = (const char*)A + (size_t)arow * (size_t)lda * 2u + (size_t)(fh * 16);
    const char* pI = srcAp;                       // AM1/2: inp rows (lda == LDA)
    const char* pA = nullptr; const char* pY = nullptr;
    if constexpr (AM == 2) {
        const int ia = b2a[arow], ir = b2revb[arow];
        pA = (const char*)aYp + (size_t)ia * (LDA * 2) + (size_t)(fh * 16);
        pY = (const char*)Yp  + (size_t)ir * (LDA * 2) + (size_t)(fh * 16);
    }
    const char* WpC = (const char*)Wp;
    const size_t srcB = (size_t)(3 * wid) * 1024u + (size_t)lane * 16u;

    f32x4 acc[2][12] = {};
    uint4 qa0, qa1, qa2, qb0, qb1, qb2;           // reg-staged A (AM1/2)
    (void)qa1; (void)qa2; (void)qb1; (void)qb2;

    // ---- prologue: tiles 0,1 in flight; tile 0 resident before loop ----
    if constexpr (AM == 0) {
        gl_lds(srcAp, (char*)As[0] + wid * 1024);
        #pragma unroll
        for (int j = 0; j < 3; ++j) gl_lds(WpC + srcB + (size_t)j * 1024, (char*)Bs[0] + 3 * wid * 1024 + j * 1024);
        gl_lds(srcAp + 64, (char*)As[1] + wid * 1024);
        #pragma unroll
        for (int j = 0; j < 3; ++j) gl_lds(WpC + (size_t)(BCH * 1024) + srcB + (size_t)j * 1024, (char*)Bs[1] + 3 * wid * 1024 + j * 1024);
        asm volatile("s_waitcnt vmcnt(4)" ::: "memory");
        __builtin_amdgcn_s_barrier();
    } else if constexpr (AM == 1) {
        qb0 = *reinterpret_cast<const uint4*>(pI);
        #pragma unroll
        for (int j = 0; j < 3; ++j) gl_lds(WpC + srcB + (size_t)j * 1024, (char*)Bs[0] + 3 * wid * 1024 + j * 1024);
        qa0 = *reinterpret_cast<const uint4*>(pI + 64);
        #pragma unroll
        for (int j = 0; j < 3; ++j) gl_lds(WpC + (size_t)(BCH * 1024) + srcB + (size_t)j * 1024, (char*)Bs[1] + 3 * wid * 1024 + j * 1024);
        asm volatile("s_waitcnt vmcnt(4)" ::: "memory");
        *reinterpret_cast<uint4*>(&As[0][wid * 512 + lane * 8]) = relu_bf16x8(qb0);
        asm volatile("s_waitcnt lgkmcnt(0)" ::: "memory");
        __builtin_amdgcn_s_barrier();
    } else {
        qb0 = *reinterpret_cast<const uint4*>(pI);
        qb1 = *reinterpret_cast<const uint4*>(pA);
        qb2 = *reinterpret_cast<const uint4*>(pY);
        #pragma unroll
        for (int j = 0; j < 3; ++j) gl_lds(WpC + srcB + (size_t)j * 1024, (char*)Bs[0] + 3 * wid * 1024 + j * 1024);
        qa0 = *reinterpret_cast<const uint4*>(pI + 64);
        qa1 = *reinterpret_cast<const uint4*>(pA + 64);
        qa2 = *reinterpret_cast<const uint4*>(pY + 64);
        #pragma unroll
        for (int j = 0; j < 3; ++j) gl_lds(WpC + (size_t)(BCH * 1024) + srcB + (size_t)j * 1024, (char*)Bs[1] + 3 * wid * 1024 + j * 1024);
        asm volatile("s_waitcnt vmcnt(6)" ::: "memory");
        *reinterpret_cast<uint4*>(&As[0][wid * 512 + lane * 8]) = comb_bf16x8(qb0, qb1, qb2);
        asm volatile("s_waitcnt lgkmcnt(0)" ::: "memory");
        __builtin_amdgcn_s_barrier();
    }

    int tt = 0, cur = 0;

#define STEP(RNi, RNa, RNy, RXi, RXa, RXy) do {                                             \
    int w2 = tt + 2; if (w2 >= NT) w2 -= NT;                                                \
    const int nx1 = (cur < 2) ? cur + 1 : 0;                                                \
    const int nx2 = (nx1 < 2) ? nx1 + 1 : 0;                                                \
    bf16x8 af0, af1, bfv[12];                                                               \
    af0 = *reinterpret_cast<const bf16x8*>(&As[cur][(wr * 2 + 0) * 512 + lane * 8]);        \
    af1 = *reinterpret_cast<const bf16x8*>(&As[cur][(wr * 2 + 1) * 512 + lane * 8]);        \
    _Pragma("unroll")                                                                       \
    for (int n = 0; n < 6; ++n)                                                             \
        bfv[n] = *reinterpret_cast<const bf16x8*>(&Bs[cur][(wc * 12 + n) * 512 + lane * 8]);\
    if constexpr (AM == 0) {                                                                \
        gl_lds(srcAp + (size_t)w2 * 64u, (char*)As[nx2] + wid * 1024);                      \
    } else if constexpr (AM == 1) {                                                         \
        RXi = *reinterpret_cast<const uint4*>(pI + (size_t)w2 * 64u);                       \
    } else {                                                                                \
        RXi = *reinterpret_cast<const uint4*>(pI + (size_t)w2 * 64u);                       \
        RXa = *reinterpret_cast<const uint4*>(pA + (size_t)w2 * 64u);                       \
        RXy = *reinterpret_cast<const uint4*>(pY + (size_t)w2 * 64u);                       \
    }                                                                                       \
    gl_lds(WpC + (size_t)w2 * (size_t)(BCH * 1024) + srcB, (char*)Bs[nx2] + 3 * wid * 1024);\
    __builtin_amdgcn_s_barrier();                                                           \
    __builtin_amdgcn_s_setprio(1);                                                          \
    _Pragma("unroll")                                                                       \
    for (int n = 0; n < 6; ++n) {                                                           \
        acc[0][n] = __builtin_amdgcn_mfma_f32_16x16x32_bf16(af0, bfv[n], acc[0][n], 0,0,0); \
        acc[1][n] = __builtin_amdgcn_mfma_f32_16x16x32_bf16(af1, bfv[n], acc[1][n], 0,0,0); \
    }                                                                                       \
    __builtin_amdgcn_s_setprio(0);                                                          \
    __builtin_amdgcn_s_barrier();                                                           \
    _Pragma("unroll")                                                                       \
    for (int n = 6; n < 12; ++n)                                                            \
        bfv[n] = *reinterpret_cast<const bf16x8*>(&Bs[cur][(wc * 12 + n) * 512 + lane * 8]);\
    gl_lds(WpC + (size_t)w2 * (size_t)(BCH * 1024) + srcB + 1024, (char*)Bs[nx2] + 3 * wid * 1024 + 1024); \
    gl_lds(WpC + (size_t)w2 * (size_t)(BCH * 1024) + srcB + 2048, (char*)Bs[nx2] + 3 * wid * 1024 + 2048); \
    if constexpr (AM == 2) { asm volatile("s_waitcnt vmcnt(6)" ::: "memory"); }             \
    else                   { asm volatile("s_waitcnt vmcnt(4)" ::: "memory"); }             \
    if constexpr (AM == 1) {                                                                \
        *reinterpret_cast<uint4*>(&As[nx1][wid * 512 + lane * 8]) = relu_bf16x8(RNi);       \
        asm volatile("s_waitcnt lgkmcnt(0)" ::: "memory");                                  \
    } else if constexpr (AM == 2) {                                                         \
        *reinterpret_cast<uint4*>(&As[nx1][wid * 512 + lane * 8]) = comb_bf16x8(RNi, RNa, RNy); \
        asm volatile("s_waitcnt lgkmcnt(0)" ::: "memory");                                  \
    }                                                                                       \
    __builtin_amdgcn_s_barrier();                                                           \
    __builtin_amdgcn_s_setprio(1);                                                          \
    _Pragma("unroll")                                                                       \
    for (int n = 6; n < 12; ++n) {                                                          \
        acc[0][n] = __builtin_amdgcn_mfma_f32_16x16x32_bf16(af0, bfv[n], acc[0][n], 0,0,0); \
        acc[1][n] = __builtin_amdgcn_mfma_f32_16x16x32_bf16(af1, bfv[n], acc[1][n], 0,0,0); \
    }                                                                                       \
    __builtin_amdgcn_s_setprio(0);                                                          \
    __builtin_amdgcn_s_barrier();                                                           \
    cur = nx1; ++tt;                                                                        \
} while (0)

    while (tt + 1 < NT) {
        STEP(qa0, qa1, qa2, qb0, qb1, qb2);
        STEP(qb0, qb1, qb2, qa0, qa1, qa2);
    }
    if (tt < NT) STEP(qa0, qa1, qa2, qb0, qb1, qb2);   // odd-NT tail (AM0 only)
#undef STEP

    // epilogue: C/D col=lane&15, row=(lane>>4)*4+reg
    #pragma unroll
    for (int m = 0; m < 2; ++m) {
        #pragma unroll
        for (int r = 0; r < 4; ++r) {
            const int row = m0 + wr * 32 + m * 16 + fh * 4 + r;
            if (row >= M) continue;
            #pragma unroll
            for (int n = 0; n < 12; ++n) {
                const int col = wc * 192 + n * 16 + fl;
                if (col >= HIDDEN) continue;
                const float v = acc[m][n][r];
                if (EPI == 0) out0[(size_t)row * ldo0 + col] = f2bu(v);
                else          out0[(size_t)row * ldo0 + col] = f2bu(fmaxf(v + bias[col], 0.f));
            }
        }
    }
}

// ---- weight -> staged panel layout with optional K-row remap:
//      col = c*16 + (l&15), k = kt*32 + (l>>4)*8 + e
//      src row r = (k<split) ? k+off1 : k-split; valid iff (k<split ? r<Ktot : r<off1)
__global__ __launch_bounds__(256) void wconv_k(const float* __restrict__ W,
                                               int split, int off1, int Ktot, int NT,
                                               u16* __restrict__ Wp)
{
    const int id = blockIdx.x * 256 + threadIdx.x;
    if (id >= NT * BCH * 512) return;
    const int block = id >> 9, rem = id & 511;
    const int l = rem >> 3, e = rem & 7;
    const int c = block % BCH, kt = block / BCH;
    const int col = c * 16 + (l & 15);
    const int k   = kt * 32 + (l >> 4) * 8 + e;
    float v = 0.f;
    if (col < HIDDEN) {
        if (k < split) {
            const int r = k + off1;
            if (r < Ktot) v = W[(size_t)r * HIDDEN + col];
        } else {
            const int r = k - split;
            if (r < off1) v = W[(size_t)r * HIDDEN + col];
        }
    }
    Wp[id] = f2bu(v);
}

// ---- f_bonds f32 -> bf16 padded [200000][160] ----
__global__ __launch_bounds__(256) void fbconv_k(const float* __restrict__ fb, u16* __restrict__ dst)
{
    const int id = blockIdx.x * 256 + threadIdx.x;
    if (id >= N_BONDS * KP_I) return;
    const int r = id / KP_I, k = id - r * KP_I;
    dst[id] = f2bu(k < BOND_FDIM ? fb[(size_t)r * BOND_FDIM + k] : 0.f);
}

// ---- dst[a][:] = sum_j src[a2b[a][j]][:]   (16B chunks, stride LDA) ----
__global__ __launch_bounds__(256) void agg_k(const u16* __restrict__ src,
                                             const int* __restrict__ a2b,
                                             u16* __restrict__ dst)
{
    const int c = blockIdx.x * 256 + threadIdx.x;
    if (c >= N_ATOMS * CPR) return;
    const int a = c / CPR, q = c - a * CPR;
    const int h = q * 8;
    const int* nb = a2b + (size_t)a * MAX_NB;
    float s[8] = {};
    #pragma unroll
    for (int j = 0; j < MAX_NB; ++j) {
        const int r = nb[j];
        union { uint4 u; u16 s[8]; } x;
        x.u = *(const uint4*)(src + (size_t)r * LDA + h);
        #pragma unroll
        for (int e = 0; e < 8; ++e) s[e] += bu2f(x.s[e]);
    }
    union { uint4 u; u16 s[8]; } o;
    #pragma unroll
    for (int e = 0; e < 8; ++e) o.s[e] = f2bu(s[e]);
    *(uint4*)(dst + (size_t)a * LDA + h) = o.u;
}

// ---- msg[b] = relu(inp[b] + aY[b2a[b]] - Y[b2revb[b]])   (16B chunks) ----
__global__ __launch_bounds__(256) void comb_k(const u16* __restrict__ inp,
                                              const u16* __restrict__ aY,
                                              const u16* __restrict__ Y,
                                              const int* __restrict__ b2a,
                                              const int* __restrict__ b2revb,
                                              u16* __restrict__ msg)
{
    const int c = blockIdx.x * 256 + threadIdx.x;
    if (c >= N_BONDS * CPR) return;
    const int b = c / CPR, q = c - b * CPR;
    const int h = q * 8;
    const int ia = b2a[b], ir = b2revb[b];
    union { uint4 u; u16 s[8]; } xi, xa, xy, o;
    xi.u = *(const uint4*)(inp + (size_t)b * LDA + h);
    xa.u = *(const uint4*)(aY + (size_t)ia * LDA + h);
    xy.u = *(const uint4*)(Y + (size_t)ir * LDA + h);
    #pragma unroll
    for (int j = 0; j < 8; ++j)
        o.s[j] = f2bu(fmaxf(bu2f(xi.s[j]) + bu2f(xa.s[j]) - bu2f(xy.s[j]), 0.f));
    *(uint4*)(msg + (size_t)b * LDA + h) = o.u;
}

// ---- fused final agg + concat (REORDERED): dst[a][k] =
//      k<300: sum_j msg[a2b[a][j]][k] | k<433: f_atoms[a][k-300] | 0 ----
__global__ __launch_bounds__(256) void aggcat_k(const u16* __restrict__ msg,
                                                const int* __restrict__ a2b,
                                                const float* __restrict__ fa,
                                                u16* __restrict__ dst)
{
    const int id = blockIdx.x * 256 + threadIdx.x;
    if (id >= N_ATOMS * (KP_O / 4)) return;
    const int a = id / (KP_O / 4), c = id - a * (KP_O / 4);
    const int e0 = c * 4;
    union { uint2 u; u16 s[4]; } o;
    if (e0 < HIDDEN) {
        const int* nb = a2b + (size_t)a * MAX_NB;
        float s0 = 0.f, s1 = 0.f, s2 = 0.f, s3 = 0.f;
        #pragma unroll
        for (int j = 0; j < MAX_NB; ++j) {
            union { uint2 u; u16 s[4]; } x;
            x.u = *(const uint2*)(msg + (size_t)nb[j] * LDA + e0);
            s0 += bu2f(x.s[0]); s1 += bu2f(x.s[1]); s2 += bu2f(x.s[2]); s3 += bu2f(x.s[3]);
        }
        o.s[0] = f2bu(s0); o.s[1] = f2bu(s1); o.s[2] = f2bu(s2); o.s[3] = f2bu(s3);
    } else {
        #pragma unroll
        for (int j = 0; j < 4; ++j) {
            const int fi = e0 + j - HIDDEN;
            o.s[j] = (fi < ATOM_FDIM) ? f2bu(fa[(size_t)a * ATOM_FDIM + fi]) : (u16)0;
        }
    }
    *(uint2*)(dst + (size_t)a * KP_O + e0) = o.u;
}

// ---- per-mol mean over sorted atom2mol ----
__global__ __launch_bounds__(320) void pool_k(const u16* __restrict__ ah,
                                              const int* __restrict__ a2m,
                                              float* __restrict__ out)
{
    const int m = blockIdx.x;
    int lo, hi;
    { int l = 0, r = N_ATOMS;
      while (l < r) { int mid = (l + r) >> 1; if (a2m[mid] < m) l = mid + 1; else r = mid; }
      lo = l; }
    { int l = lo, r = N_ATOMS;
      while (l < r) { int mid = (l + r) >> 1; if (a2m[mid] < m + 1) l = mid + 1; else r = mid; }
      hi = l; }
    const float inv = 1.0f / (float)((hi - lo) > 1 ? (hi - lo) : 1);
    const int h = threadIdx.x;
    if (h >= HIDDEN) return;
    float s = 0.f;
    for (int a = lo; a < hi; ++a) s += bu2f(ah[(size_t)a * LDA + h]);
    out[(size_t)m * HIDDEN + h] = s * inv;
}

extern "C" void kernel_launch(void* const* d_in, const int* in_sizes, int n_in,
                              void* d_out, int out_size, void* d_ws, size_t ws_size,
                              hipStream_t stream)
{
    const float* f_atoms  = (const float*)d_in[0];
    const float* f_bonds  = (const float*)d_in[1];
    const int*   a2b      = (const int*)d_in[2];
    const int*   b2a      = (const int*)d_in[3];
    const int*   b2revb   = (const int*)d_in[4];
    const int*   atom2mol = (const int*)d_in[5];
    const float* W_i      = (const float*)d_in[6];
    const float* W_h      = (const float*)d_in[7];
    const float* W_o_w    = (const float*)d_in[8];
    const float* W_o_b    = (const float*)d_in[9];
    float* out = (float*)d_out;

    // ---- workspace (bf16 as u16); +16 rows slack per big buffer ----
    char* p = (char*)d_ws;
    auto alloc = [&](size_t bytes) { char* r = p; p += (bytes + 255) & ~(size_t)255; return r; };
    u16* B0 = (u16*)alloc(((size_t)N_BONDS + 16) * LDA * 2);   // inp, later ah
    u16* B1 = (u16*)alloc(((size_t)N_BONDS + 16) * LDA * 2);   // fb16 -> Y1 -> msg2
    u16* B2 = (u16*)alloc(((size_t)N_BONDS + 16) * LDA * 2);   // Y2 -> concat
    u16* aY = (u16*)alloc(((size_t)N_ATOMS + 16) * LDA * 2);
    u16* Wpi = (u16*)alloc((size_t)(KP_I / 32) * BCH * 512 * 2);
    u16* Wph = (u16*)alloc((size_t)(KP_H / 32) * BCH * 512 * 2);
    u16* Wpo = (u16*)alloc((size_t)(KP_O / 32) * BCH * 512 * 2);
    if ((size_t)(p - (char*)d_ws) > ws_size) return;

    u16* inp    = B0;
    u16* fb16   = B1;   // dead after mm<0>
    u16* Y1     = B1;
    u16* Y2     = B2;
    u16* msg2   = B1;   // Y1 dead after AM2 GEMM
    u16* concat = B2;   // Y2 dead after comb
    u16* ah     = B0;   // inp dead after comb

    const dim3 blk(256);
    auto g1 = [](long long n) { return dim3((unsigned)((n + 255) / 256)); };
    const dim3 blk5(512);
    const dim3 gB((N_BONDS + TM - 1) / TM);   // 1563
    const dim3 gA((N_ATOMS + TM - 1) / TM);   //  782

    const int BIGSPLIT = 1 << 20;
    wconv_k<<<g1((long long)(KP_I / 32) * BCH * 512), blk, 0, stream>>>(
        W_i, BIGSPLIT, 0, BOND_FDIM, KP_I / 32, Wpi);
    wconv_k<<<g1((long long)(KP_H / 32) * BCH * 512), blk, 0, stream>>>(
        W_h, BIGSPLIT, 0, HIDDEN, KP_H / 32, Wph);
    wconv_k<<<g1((long long)(KP_O / 32) * BCH * 512), blk, 0, stream>>>(
        W_o_w, HIDDEN, ATOM_FDIM, ATOM_FDIM + HIDDEN, KP_O / 32, Wpo);
    fbconv_k<<<g1((long long)N_BONDS * KP_I), blk, 0, stream>>>(f_bonds, fb16);

    // inp = f_bonds @ W_i (raw only; relu fused into the next GEMM's A-stage)
    mm_k<0, 0><<<gB, blk5, 0, stream>>>(fb16, KP_I, nullptr, nullptr, nullptr, nullptr,
                                        Wpi, nullptr, inp, LDA, N_BONDS, KP_I / 32);

    // iter 1: Y1 = relu(inp) @ W_h        (msg0 never materialized)
    mm_k<1, 0><<<gB, blk5, 0, stream>>>(inp, LDA, nullptr, nullptr, nullptr, nullptr,
                                        Wph, nullptr, Y1, LDA, N_BONDS, KP_H / 32);
    agg_k<<<g1((long long)N_ATOMS * CPR), blk, 0, stream>>>(Y1, a2b, aY);

    // iter 2: Y2 = relu(inp + aY[b2a] - Y1[b2revb]) @ W_h   (msg1 never materialized)
    mm_k<2, 0><<<gB, blk5, 0, stream>>>(inp, LDA, aY, Y1, b2a, b2revb,
                                        Wph, nullptr, Y2, LDA, N_BONDS, KP_H / 32);
    agg_k<<<g1((long long)N_ATOMS * CPR), blk, 0, stream>>>(Y2, a2b, aY);

    // msg2 materialized (feeds the 6-way aggcat gather)
    comb_k<<<g1((long long)N_BONDS * CPR), blk, 0, stream>>>(inp, aY, Y2, b2a, b2revb, msg2);
    aggcat_k<<<g1((long long)N_ATOMS * (KP_O / 4)), blk, 0, stream>>>(msg2, a2b, f_atoms, concat);

    mm_k<0, 1><<<gA, blk5, 0, stream>>>(concat, KP_O, nullptr, nullptr, nullptr, nullptr,
                                        Wpo, W_o_b, ah, LDA, N_ATOMS, KP_O / 32);
    pool_k<<<dim3(N_MOLS), dim3(320), 0, stream>>>(ah, atom2mol, out);
}

// Round 9
// 879.779 us; speedup vs baseline: 1.1614x; 1.0053x over previous
//
#include <hip/hip_runtime.h>
#include <stdint.h>

#define ATOM_FDIM 133
#define BOND_FDIM 147
#define HIDDEN    300
#define N_ATOMS   100000
#define N_BONDS   200000
#define MAX_NB    6
#define N_MOLS    4000

#define KP_I 160      // padded K for W_i GEMM (147)
#define KP_H 320      // padded K for W_h GEMM (300)
#define KP_O 448      // padded K for output GEMM (433, reordered: amsg|f_atoms|0)
#define LDA  304      // activation row stride in elems (608B, 16B-aligned)
#define CPR  38       // uint4 chunks per activation row (304/8)

#define TM   128      // GEMM tile rows
#define ACH  8        // A chunks (1KB) per K-tile
#define BCH  24       // B chunks (1KB) per K-tile

typedef unsigned short u16;
typedef short bf16x8 __attribute__((ext_vector_type(8)));
typedef float f32x4 __attribute__((ext_vector_type(4)));

__device__ __forceinline__ u16 f2bu(float f) {            // f32 -> bf16 (RNE)
    unsigned u = __float_as_uint(f);
    u += 0x7FFFu + ((u >> 16) & 1u);
    return (u16)(u >> 16);
}
__device__ __forceinline__ float bu2f(u16 b) { return __uint_as_float(((unsigned)b) << 16); }

__device__ __forceinline__ uint4 relu_bf16x8(uint4 v) {
    union { uint4 u; u16 s[8]; } x, o;
    x.u = v;
    #pragma unroll
    for (int e = 0; e < 8; ++e) o.s[e] = (x.s[e] & 0x8000u) ? (u16)0 : x.s[e];
    return o.u;
}
__device__ __forceinline__ uint4 comb_bf16x8(uint4 vi, uint4 va, uint4 vy) {
    union { uint4 u; u16 s[8]; } xi, xa, xy, o;
    xi.u = vi; xa.u = va; xy.u = vy;
    #pragma unroll
    for (int e = 0; e < 8; ++e)
        o.s[e] = f2bu(fmaxf(bu2f(xi.s[e]) + bu2f(xa.s[e]) - bu2f(xy.s[e]), 0.f));
    return o.u;
}

#define AS1 __attribute__((address_space(1)))
#define AS3 __attribute__((address_space(3)))
__device__ __forceinline__ void gl_lds(const void* g, void* l) {
    __builtin_amdgcn_global_load_lds((const AS1 void*)g, (AS3 void*)l, 16, 0, 0);
}

// ---------- dense bf16 MFMA GEMM ----------
// Block: 128 rows x 384 cols, 512 threads (8 waves, 4x2). Wave: 32 rows x 192
// cols = 2x12 frags of 16x16x32.
// AM0: A via global_load_lds, tri-buffered A/B, stage t+2, gate vmcnt(4) (r5-proven).
// AM1/AM2: A computed on the fly (relu(inp) / relu(inp+aY[b2a]-Y[b2revb])).
//   3 rotating reg sets: per-lane A loads issued for tile t+3 (2.6-step cover vs
//   ~900cyc HBM latency), B quad-buffered staged t+3 (issue order A then B keeps
//   the in-order vmcnt queue monotone in need-time), As double-buffered with
//   ds_write 1-ahead after the gate. Gate vmcnt(8) AM1 / vmcnt(12) AM2 — waits
//   only ops >=2 steps old; never drains the prefetch.
// EPI 0: out0 = raw | 1: out0 = relu(v + bias)
template <int AM, int EPI>
__global__ __launch_bounds__(512, 2) void mm_k(
    const u16* __restrict__ A, int lda,          // AM0: dense A; AM1/2: inp
    const u16* __restrict__ aYp,                 // AM2
    const u16* __restrict__ Yp,                  // AM2
    const int* __restrict__ b2a,                 // AM2
    const int* __restrict__ b2revb,              // AM2
    const u16* __restrict__ Wp,                  // panel layout: [NT][BCH][512] elems
    const float* __restrict__ bias,
    u16* __restrict__ out0, int ldo0,
    int M, int NT)                               // AM0: NT>=3; AM1/2: NT>=4
{
    constexpr int NBA = (AM == 0) ? 3 : 2;
    constexpr int NBB = (AM == 0) ? 3 : 4;
    __shared__ __align__(16) u16 As[NBA * ACH * 512];
    __shared__ __align__(16) u16 Bs[NBB * BCH * 512];

    const int t    = threadIdx.x;
    const int lane = t & 63, wid = t >> 6;
    const int fl   = lane & 15, fh = lane >> 4;
    const int m0   = blockIdx.x * TM;
    const int wr   = wid >> 1, wc = wid & 1;

    int arow = m0 + wid * 16 + fl;
    if (arow > M - 1) arow = M - 1;
    const char* srcAp = (const char*)A + (size_t)arow * (size_t)lda * 2u + (size_t)(fh * 16);
    const char* pI = srcAp;                       // AM1/2: inp rows (lda == LDA)
    const char* pA = nullptr; const char* pY = nullptr;
    if constexpr (AM == 2) {
        const int ia = b2a[arow], ir = b2revb[arow];
        pA = (const char*)aYp + (size_t)ia * (LDA * 2) + (size_t)(fh * 16);
        pY = (const char*)Yp  + (size_t)ir * (LDA * 2) + (size_t)(fh * 16);
    }
    const char* WpC = (const char*)Wp;
    const size_t srcB = (size_t)(3 * wid) * 1024u + (size_t)lane * 16u;

    f32x4 acc[2][12] = {};
    int tt = 0;

    if constexpr (AM == 0) {
        // ================= AM0: r5-proven tri-buffer path =================
        gl_lds(srcAp, (char*)As + wid * 1024);
        #pragma unroll
        for (int j = 0; j < 3; ++j)
            gl_lds(WpC + srcB + (size_t)j * 1024, (char*)Bs + 3 * wid * 1024 + j * 1024);
        gl_lds(srcAp + 64, (char*)As + (ACH * 1024) + wid * 1024);
        #pragma unroll
        for (int j = 0; j < 3; ++j)
            gl_lds(WpC + (size_t)(BCH * 1024) + srcB + (size_t)j * 1024,
                   (char*)Bs + (BCH * 1024) + 3 * wid * 1024 + j * 1024);
        asm volatile("s_waitcnt vmcnt(4)" ::: "memory");
        __builtin_amdgcn_s_barrier();

        int cur = 0;
        for (tt = 0; tt < NT; ++tt) {
            int w2 = tt + 2; if (w2 >= NT) w2 -= NT;
            const int nx1 = (cur < 2) ? cur + 1 : 0;
            const int nx2 = (nx1 < 2) ? nx1 + 1 : 0;
            const u16* as_c = As + (size_t)cur * (ACH * 512);
            const u16* bs_c = Bs + (size_t)cur * (BCH * 512);
            const size_t kbB = (size_t)w2 * (size_t)(BCH * 1024);

            bf16x8 af0, af1, bfv[12];
            af0 = *reinterpret_cast<const bf16x8*>(&as_c[(wr * 2 + 0) * 512 + lane * 8]);
            af1 = *reinterpret_cast<const bf16x8*>(&as_c[(wr * 2 + 1) * 512 + lane * 8]);
            #pragma unroll
            for (int n = 0; n < 6; ++n)
                bfv[n] = *reinterpret_cast<const bf16x8*>(&bs_c[(wc * 12 + n) * 512 + lane * 8]);
            gl_lds(srcAp + (size_t)w2 * 64u, (char*)As + (size_t)nx2 * (ACH * 1024) + wid * 1024);
            gl_lds(WpC + kbB + srcB, (char*)Bs + (size_t)nx2 * (BCH * 1024) + 3 * wid * 1024);
            __builtin_amdgcn_s_barrier();
            __builtin_amdgcn_s_setprio(1);
            #pragma unroll
            for (int n = 0; n < 6; ++n) {
                acc[0][n] = __builtin_amdgcn_mfma_f32_16x16x32_bf16(af0, bfv[n], acc[0][n], 0, 0, 0);
                acc[1][n] = __builtin_amdgcn_mfma_f32_16x16x32_bf16(af1, bfv[n], acc[1][n], 0, 0, 0);
            }
            __builtin_amdgcn_s_setprio(0);
            __builtin_amdgcn_s_barrier();

            #pragma unroll
            for (int n = 6; n < 12; ++n)
                bfv[n] = *reinterpret_cast<const bf16x8*>(&bs_c[(wc * 12 + n) * 512 + lane * 8]);
            gl_lds(WpC + kbB + srcB + 1024, (char*)Bs + (size_t)nx2 * (BCH * 1024) + 3 * wid * 1024 + 1024);
            gl_lds(WpC + kbB + srcB + 2048, (char*)Bs + (size_t)nx2 * (BCH * 1024) + 3 * wid * 1024 + 2048);
            asm volatile("s_waitcnt vmcnt(4)" ::: "memory");
            __builtin_amdgcn_s_barrier();
            __builtin_amdgcn_s_setprio(1);
            #pragma unroll
            for (int n = 6; n < 12; ++n) {
                acc[0][n] = __builtin_amdgcn_mfma_f32_16x16x32_bf16(af0, bfv[n], acc[0][n], 0, 0, 0);
                acc[1][n] = __builtin_amdgcn_mfma_f32_16x16x32_bf16(af1, bfv[n], acc[1][n], 0, 0, 0);
            }
            __builtin_amdgcn_s_setprio(0);
            __builtin_amdgcn_s_barrier();
            cur = nx1;
        }
    } else {
        // ========== AM1/AM2: 3-deep reg-staged A, quad-buffered B ==========
        uint4 Xi, Xa, Xy, Yi, Ya, Yy, Zi, Za, Zy;
        (void)Xa; (void)Xy; (void)Ya; (void)Yy; (void)Za; (void)Zy;

        // prologue (issue order monotone in need-time): A0,B0,A1,B1,A2,B2
        Xi = *reinterpret_cast<const uint4*>(pI);
        if constexpr (AM == 2) { Xa = *reinterpret_cast<const uint4*>(pA);
                                 Xy = *reinterpret_cast<const uint4*>(pY); }
        #pragma unroll
        for (int j = 0; j < 3; ++j)
            gl_lds(WpC + srcB + (size_t)j * 1024, (char*)Bs + 3 * wid * 1024 + j * 1024);
        Yi = *reinterpret_cast<const uint4*>(pI + 64);
        if constexpr (AM == 2) { Ya = *reinterpret_cast<const uint4*>(pA + 64);
                                 Yy = *reinterpret_cast<const uint4*>(pY + 64); }
        #pragma unroll
        for (int j = 0; j < 3; ++j)
            gl_lds(WpC + (size_t)(BCH * 1024) + srcB + (size_t)j * 1024,
                   (char*)Bs + (BCH * 1024) + 3 * wid * 1024 + j * 1024);
        Zi = *reinterpret_cast<const uint4*>(pI + 128);
        if constexpr (AM == 2) { Za = *reinterpret_cast<const uint4*>(pA + 128);
                                 Zy = *reinterpret_cast<const uint4*>(pY + 128); }
        #pragma unroll
        for (int j = 0; j < 3; ++j)
            gl_lds(WpC + (size_t)(2 * BCH * 1024) + srcB + (size_t)j * 1024,
                   (char*)Bs + (2 * BCH * 1024) + 3 * wid * 1024 + j * 1024);
        if constexpr (AM == 2) { asm volatile("s_waitcnt vmcnt(12)" ::: "memory"); }
        else                   { asm volatile("s_waitcnt vmcnt(8)"  ::: "memory"); }
        {
            uint4 w0;
            if constexpr (AM == 2) w0 = comb_bf16x8(Xi, Xa, Xy);
            else                   w0 = relu_bf16x8(Xi);
            *reinterpret_cast<uint4*>(&As[wid * 512 + lane * 8]) = w0;
        }
        asm volatile("s_waitcnt lgkmcnt(0)" ::: "memory");
        __builtin_amdgcn_s_barrier();

#define STEP12(Ui, Ua, Uy, Vi, Va, Vy, Wi, Wa, Wy) do {                                     \
    int w3 = tt + 3; if (w3 >= NT) w3 -= NT;                                                \
    const u16* as_c = As + (size_t)(tt & 1) * (ACH * 512);                                  \
    const u16* bs_c = Bs + (size_t)(tt & 3) * (BCH * 512);                                  \
    char* bst = (char*)Bs + (size_t)((tt + 3) & 3) * (BCH * 1024) + 3 * wid * 1024;         \
    const size_t kbB = (size_t)w3 * (size_t)(BCH * 1024);                                   \
    bf16x8 af0, af1, bfv[12];                                                               \
    af0 = *reinterpret_cast<const bf16x8*>(&as_c[(wr * 2 + 0) * 512 + lane * 8]);           \
    af1 = *reinterpret_cast<const bf16x8*>(&as_c[(wr * 2 + 1) * 512 + lane * 8]);           \
    _Pragma("unroll")                                                                       \
    for (int n = 0; n < 6; ++n)                                                             \
        bfv[n] = *reinterpret_cast<const bf16x8*>(&bs_c[(wc * 12 + n) * 512 + lane * 8]);   \
    Wi = *reinterpret_cast<const uint4*>(pI + (size_t)w3 * 64u);                            \
    if constexpr (AM == 2) {                                                                \
        Wa = *reinterpret_cast<const uint4*>(pA + (size_t)w3 * 64u);                        \
        Wy = *reinterpret_cast<const uint4*>(pY + (size_t)w3 * 64u);                        \
    }                                                                                       \
    gl_lds(WpC + kbB + srcB, bst);                                                          \
    __builtin_amdgcn_s_barrier();                                                           \
    __builtin_amdgcn_s_setprio(1);                                                          \
    _Pragma("unroll")                                                                       \
    for (int n = 0; n < 6; ++n) {                                                           \
        acc[0][n] = __builtin_amdgcn_mfma_f32_16x16x32_bf16(af0, bfv[n], acc[0][n], 0,0,0); \
        acc[1][n] = __builtin_amdgcn_mfma_f32_16x16x32_bf16(af1, bfv[n], acc[1][n], 0,0,0); \
    }                                                                                       \
    __builtin_amdgcn_s_setprio(0);                                                          \
    __builtin_amdgcn_s_barrier();                                                           \
    _Pragma("unroll")                                                                       \
    for (int n = 6; n < 12; ++n)                                                            \
        bfv[n] = *reinterpret_cast<const bf16x8*>(&bs_c[(wc * 12 + n) * 512 + lane * 8]);   \
    gl_lds(WpC + kbB + srcB + 1024, bst + 1024);                                            \
    gl_lds(WpC + kbB + srcB + 2048, bst + 2048);                                            \
    if constexpr (AM == 2) { asm volatile("s_waitcnt vmcnt(12)" ::: "memory"); }            \
    else                   { asm volatile("s_waitcnt vmcnt(8)"  ::: "memory"); }            \
    {                                                                                       \
        uint4 wv;                                                                           \
        if constexpr (AM == 2) wv = comb_bf16x8(Ui, Ua, Uy);                                \
        else                   wv = relu_bf16x8(Ui);                                        \
        *reinterpret_cast<uint4*>(&As[(size_t)((tt + 1) & 1) * (ACH * 512)                  \
                                      + wid * 512 + lane * 8]) = wv;                        \
    }                                                                                       \
    asm volatile("s_waitcnt lgkmcnt(0)" ::: "memory");                                      \
    __builtin_amdgcn_s_barrier();                                                           \
    __builtin_amdgcn_s_setprio(1);                                                          \
    _Pragma("unroll")                                                                       \
    for (int n = 6; n < 12; ++n) {                                                          \
        acc[0][n] = __builtin_amdgcn_mfma_f32_16x16x32_bf16(af0, bfv[n], acc[0][n], 0,0,0); \
        acc[1][n] = __builtin_amdgcn_mfma_f32_16x16x32_bf16(af1, bfv[n], acc[1][n], 0,0,0); \
    }                                                                                       \
    __builtin_amdgcn_s_setprio(0);                                                          \
    __builtin_amdgcn_s_barrier();                                                           \
    ++tt;                                                                                   \
} while (0)

        while (tt + 2 < NT) {
            STEP12(Yi, Ya, Yy, Zi, Za, Zy, Xi, Xa, Xy);
            STEP12(Zi, Za, Zy, Xi, Xa, Xy, Yi, Ya, Yy);
            STEP12(Xi, Xa, Xy, Yi, Ya, Yy, Zi, Za, Zy);
        }
        if (tt < NT) STEP12(Yi, Ya, Yy, Zi, Za, Zy, Xi, Xa, Xy);
        if (tt < NT) STEP12(Zi, Za, Zy, Xi, Xa, Xy, Yi, Ya, Yy);
#undef STEP12
    }

    // epilogue: C/D col=lane&15, row=(lane>>4)*4+reg
    #pragma unroll
    for (int m = 0; m < 2; ++m) {
        #pragma unroll
        for (int r = 0; r < 4; ++r) {
            const int row = m0 + wr * 32 + m * 16 + fh * 4 + r;
            if (row >= M) continue;
            #pragma unroll
            for (int n = 0; n < 12; ++n) {
                const int col = wc * 192 + n * 16 + fl;
                if (col >= HIDDEN) continue;
                const float v = acc[m][n][r];
                if (EPI == 0) out0[(size_t)row * ldo0 + col] = f2bu(v);
                else          out0[(size_t)row * ldo0 + col] = f2bu(fmaxf(v + bias[col], 0.f));
            }
        }
    }
}

// ---- weight -> staged panel layout with optional K-row remap:
//      col = c*16 + (l&15), k = kt*32 + (l>>4)*8 + e
//      src row r = (k<split) ? k+off1 : k-split; valid iff (k<split ? r<Ktot : r<off1)
__global__ __launch_bounds__(256) void wconv_k(const float* __restrict__ W,
                                               int split, int off1, int Ktot, int NT,
                                               u16* __restrict__ Wp)
{
    const int id = blockIdx.x * 256 + threadIdx.x;
    if (id >= NT * BCH * 512) return;
    const int block = id >> 9, rem = id & 511;
    const int l = rem >> 3, e = rem & 7;
    const int c = block % BCH, kt = block / BCH;
    const int col = c * 16 + (l & 15);
    const int k   = kt * 32 + (l >> 4) * 8 + e;
    float v = 0.f;
    if (col < HIDDEN) {
        if (k < split) {
            const int r = k + off1;
            if (r < Ktot) v = W[(size_t)r * HIDDEN + col];
        } else {
            const int r = k - split;
            if (r < off1) v = W[(size_t)r * HIDDEN + col];
        }
    }
    Wp[id] = f2bu(v);
}

// ---- f_bonds f32 -> bf16 padded [200000][160] ----
__global__ __launch_bounds__(256) void fbconv_k(const float* __restrict__ fb, u16* __restrict__ dst)
{
    const int id = blockIdx.x * 256 + threadIdx.x;
    if (id >= N_BONDS * KP_I) return;
    const int r = id / KP_I, k = id - r * KP_I;
    dst[id] = f2bu(k < BOND_FDIM ? fb[(size_t)r * BOND_FDIM + k] : 0.f);
}

// ---- dst[a][:] = sum_j src[a2b[a][j]][:]   (16B chunks, stride LDA) ----
__global__ __launch_bounds__(256) void agg_k(const u16* __restrict__ src,
                                             const int* __restrict__ a2b,
                                             u16* __restrict__ dst)
{
    const int c = blockIdx.x * 256 + threadIdx.x;
    if (c >= N_ATOMS * CPR) return;
    const int a = c / CPR, q = c - a * CPR;
    const int h = q * 8;
    const int* nb = a2b + (size_t)a * MAX_NB;
    float s[8] = {};
    #pragma unroll
    for (int j = 0; j < MAX_NB; ++j) {
        const int r = nb[j];
        union { uint4 u; u16 s[8]; } x;
        x.u = *(const uint4*)(src + (size_t)r * LDA + h);
        #pragma unroll
        for (int e = 0; e < 8; ++e) s[e] += bu2f(x.s[e]);
    }
    union { uint4 u; u16 s[8]; } o;
    #pragma unroll
    for (int e = 0; e < 8; ++e) o.s[e] = f2bu(s[e]);
    *(uint4*)(dst + (size_t)a * LDA + h) = o.u;
}

// ---- msg[b] = relu(inp[b] + aY[b2a[b]] - Y[b2revb[b]])   (16B chunks) ----
__global__ __launch_bounds__(256) void comb_k(const u16* __restrict__ inp,
                                              const u16* __restrict__ aY,
                                              const u16* __restrict__ Y,
                                              const int* __restrict__ b2a,
                                              const int* __restrict__ b2revb,
                                              u16* __restrict__ msg)
{
    const int c = blockIdx.x * 256 + threadIdx.x;
    if (c >= N_BONDS * CPR) return;
    const int b = c / CPR, q = c - b * CPR;
    const int h = q * 8;
    const int ia = b2a[b], ir = b2revb[b];
    union { uint4 u; u16 s[8]; } xi, xa, xy, o;
    xi.u = *(const uint4*)(inp + (size_t)b * LDA + h);
    xa.u = *(const uint4*)(aY + (size_t)ia * LDA + h);
    xy.u = *(const uint4*)(Y + (size_t)ir * LDA + h);
    #pragma unroll
    for (int j = 0; j < 8; ++j)
        o.s[j] = f2bu(fmaxf(bu2f(xi.s[j]) + bu2f(xa.s[j]) - bu2f(xy.s[j]), 0.f));
    *(uint4*)(msg + (size_t)b * LDA + h) = o.u;
}

// ---- fused final agg + concat (REORDERED): dst[a][k] =
//      k<300: sum_j msg[a2b[a][j]][k] | k<433: f_atoms[a][k-300] | 0 ----
__global__ __launch_bounds__(256) void aggcat_k(const u16* __restrict__ msg,
                                                const int* __restrict__ a2b,
                                                const float* __restrict__ fa,
                                                u16* __restrict__ dst)
{
    const int id = blockIdx.x * 256 + threadIdx.x;
    if (id >= N_ATOMS * (KP_O / 4)) return;
    const int a = id / (KP_O / 4), c = id - a * (KP_O / 4);
    const int e0 = c * 4;
    union { uint2 u; u16 s[4]; } o;
    if (e0 < HIDDEN) {
        const int* nb = a2b + (size_t)a * MAX_NB;
        float s0 = 0.f, s1 = 0.f, s2 = 0.f, s3 = 0.f;
        #pragma unroll
        for (int j = 0; j < MAX_NB; ++j) {
            union { uint2 u; u16 s[4]; } x;
            x.u = *(const uint2*)(msg + (size_t)nb[j] * LDA + e0);
            s0 += bu2f(x.s[0]); s1 += bu2f(x.s[1]); s2 += bu2f(x.s[2]); s3 += bu2f(x.s[3]);
        }
        o.s[0] = f2bu(s0); o.s[1] = f2bu(s1); o.s[2] = f2bu(s2); o.s[3] = f2bu(s3);
    } else {
        #pragma unroll
        for (int j = 0; j < 4; ++j) {
            const int fi = e0 + j - HIDDEN;
            o.s[j] = (fi < ATOM_FDIM) ? f2bu(fa[(size_t)a * ATOM_FDIM + fi]) : (u16)0;
        }
    }
    *(uint2*)(dst + (size_t)a * KP_O + e0) = o.u;
}

// ---- per-mol mean over sorted atom2mol ----
__global__ __launch_bounds__(320) void pool_k(const u16* __restrict__ ah,
                                              const int* __restrict__ a2m,
                                              float* __restrict__ out)
{
    const int m = blockIdx.x;
    int lo, hi;
    { int l = 0, r = N_ATOMS;
      while (l < r) { int mid = (l + r) >> 1; if (a2m[mid] < m) l = mid + 1; else r = mid; }
      lo = l; }
    { int l = lo, r = N_ATOMS;
      while (l < r) { int mid = (l + r) >> 1; if (a2m[mid] < m + 1) l = mid + 1; else r = mid; }
      hi = l; }
    const float inv = 1.0f / (float)((hi - lo) > 1 ? (hi - lo) : 1);
    const int h = threadIdx.x;
    if (h >= HIDDEN) return;
    float s = 0.f;
    for (int a = lo; a < hi; ++a) s += bu2f(ah[(size_t)a * LDA + h]);
    out[(size_t)m * HIDDEN + h] = s * inv;
}

extern "C" void kernel_launch(void* const* d_in, const int* in_sizes, int n_in,
                              void* d_out, int out_size, void* d_ws, size_t ws_size,
                              hipStream_t stream)
{
    const float* f_atoms  = (const float*)d_in[0];
    const float* f_bonds  = (const float*)d_in[1];
    const int*   a2b      = (const int*)d_in[2];
    const int*   b2a      = (const int*)d_in[3];
    const int*   b2revb   = (const int*)d_in[4];
    const int*   atom2mol = (const int*)d_in[5];
    const float* W_i      = (const float*)d_in[6];
    const float* W_h      = (const float*)d_in[7];
    const float* W_o_w    = (const float*)d_in[8];
    const float* W_o_b    = (const float*)d_in[9];
    float* out = (float*)d_out;

    // ---- workspace (bf16 as u16); +16 rows slack per big buffer ----
    char* p = (char*)d_ws;
    auto alloc = [&](size_t bytes) { char* r = p; p += (bytes + 255) & ~(size_t)255; return r; };
    u16* B0 = (u16*)alloc(((size_t)N_BONDS + 16) * LDA * 2);   // inp, later ah
    u16* B1 = (u16*)alloc(((size_t)N_BONDS + 16) * LDA * 2);   // fb16 -> Y1 -> msg2
    u16* B2 = (u16*)alloc(((size_t)N_BONDS + 16) * LDA * 2);   // Y2 -> concat
    u16* aY = (u16*)alloc(((size_t)N_ATOMS + 16) * LDA * 2);
    u16* Wpi = (u16*)alloc((size_t)(KP_I / 32) * BCH * 512 * 2);
    u16* Wph = (u16*)alloc((size_t)(KP_H / 32) * BCH * 512 * 2);
    u16* Wpo = (u16*)alloc((size_t)(KP_O / 32) * BCH * 512 * 2);
    if ((size_t)(p - (char*)d_ws) > ws_size) return;

    u16* inp    = B0;
    u16* fb16   = B1;   // dead after mm<0>
    u16* Y1     = B1;
    u16* Y2     = B2;
    u16* msg2   = B1;   // Y1 dead after AM2 GEMM
    u16* concat = B2;   // Y2 dead after comb
    u16* ah     = B0;   // inp dead after comb

    const dim3 blk(256);
    auto g1 = [](long long n) { return dim3((unsigned)((n + 255) / 256)); };
    const dim3 blk5(512);
    const dim3 gB((N_BONDS + TM - 1) / TM);   // 1563
    const dim3 gA((N_ATOMS + TM - 1) / TM);   //  782

    const int BIGSPLIT = 1 << 20;
    wconv_k<<<g1((long long)(KP_I / 32) * BCH * 512), blk, 0, stream>>>(
        W_i, BIGSPLIT, 0, BOND_FDIM, KP_I / 32, Wpi);
    wconv_k<<<g1((long long)(KP_H / 32) * BCH * 512), blk, 0, stream>>>(
        W_h, BIGSPLIT, 0, HIDDEN, KP_H / 32, Wph);
    wconv_k<<<g1((long long)(KP_O / 32) * BCH * 512), blk, 0, stream>>>(
        W_o_w, HIDDEN, ATOM_FDIM, ATOM_FDIM + HIDDEN, KP_O / 32, Wpo);
    fbconv_k<<<g1((long long)N_BONDS * KP_I), blk, 0, stream>>>(f_bonds, fb16);

    // inp = f_bonds @ W_i (raw only; relu fused into the next GEMM's A-stage)
    mm_k<0, 0><<<gB, blk5, 0, stream>>>(fb16, KP_I, nullptr, nullptr, nullptr, nullptr,
                                        Wpi, nullptr, inp, LDA, N_BONDS, KP_I / 32);

    // iter 1: Y1 = relu(inp) @ W_h        (msg0 never materialized)
    mm_k<1, 0><<<gB, blk5, 0, stream>>>(inp, LDA, nullptr, nullptr, nullptr, nullptr,
                                        Wph, nullptr, Y1, LDA, N_BONDS, KP_H / 32);
    agg_k<<<g1((long long)N_ATOMS * CPR), blk, 0, stream>>>(Y1, a2b, aY);

    // iter 2: Y2 = relu(inp + aY[b2a] - Y1[b2revb]) @ W_h   (msg1 never materialized)
    mm_k<2, 0><<<gB, blk5, 0, stream>>>(inp, LDA, aY, Y1, b2a, b2revb,
                                        Wph, nullptr, Y2, LDA, N_BONDS, KP_H / 32);
    agg_k<<<g1((long long)N_ATOMS * CPR), blk, 0, stream>>>(Y2, a2b, aY);

    // msg2 materialized (feeds the 6-way aggcat gather)
    comb_k<<<g1((long long)N_BONDS * CPR), blk, 0, stream>>>(inp, aY, Y2, b2a, b2revb, msg2);
    aggcat_k<<<g1((long long)N_ATOMS * (KP_O / 4)), blk, 0, stream>>>(msg2, a2b, f_atoms, concat);

    mm_k<0, 1><<<gA, blk5, 0, stream>>>(concat, KP_O, nullptr, nullptr, nullptr, nullptr,
                                        Wpo, W_o_b, ah, LDA, N_ATOMS, KP_O / 32);
    pool_k<<<dim3(N_MOLS), dim3(320), 0, stream>>>(ah, atom2mol, out);
}